// Round 11
// baseline (521.823 us; speedup 1.0000x reference)
//
#include <hip/hip_runtime.h>

#define N_NODES 8192
#define DEGREE 32
#define N_EDGES (N_NODES * DEGREE)
#define D_FEAT 256
#define SLICE_F 32                    // features per slice
#define N_SLICES 8                    // 8 slices; bf16 slice = 0.5 MB; slice = XCD
#define RPW 8                         // rows per wave
#define WPB 4                         // waves per block
#define RPB (RPW * WPB)               // 32 rows per block
#define NB (N_SLICES * (N_NODES / RPB))  // 8 * 256 = 2048 blocks = 8/CU

typedef unsigned int u32;
typedef unsigned short u16;

__device__ __forceinline__ float bf2f(u16 u) {
  union { u32 i; float f; } c; c.i = ((u32)u) << 16; return c.f;
}
__device__ __forceinline__ u16 f2bf(float x) {
  union { float f; u32 i; } c; c.f = x;
  u32 r = c.i + 0x7FFFu + ((c.i >> 16) & 1u);
  return (u16)(r >> 16);
}

// ---------------------------------------------------------------------------
// Prep: row-normalize once; split edges into u16 node ids (0.5 MB) and f32
// weights (1 MB) so the per-XCD L2 working set stays < 4 MiB.
// ---------------------------------------------------------------------------
__global__ __launch_bounds__(256) void prep_kernel(
    const int* __restrict__ dst, const float* __restrict__ e,
    u16* __restrict__ dst16, float* __restrict__ w32) {
  int g = blockIdx.x * 256 + threadIdx.x;
  float v = e[g];
  float s = v;
  for (int m = 1; m < 32; m <<= 1) s += __shfl_xor(s, m, 32);  // rows 32-aligned
  dst16[g] = (u16)dst[g];
  w32[g]   = v / s;
}

// ---------------------------------------------------------------------------
// y = A @ x, 8-way feature-sliced, bf16 iterate, f32 math.
// x/y layout: [N_SLICES][N_NODES][SLICE_F] bf16 (0.5 MB per slice).
// slice = blockIdx%8 -> one XCD per slice; per-XCD L2 working set:
//   x(0.5) + y(0.5) + dst16(0.5) + w32(1.0) = 2.5 MB < 4 MiB.
// Wave: lane = r2*32 + f; one gather instruction covers 2 rows (r2) x 64 B.
// 8 rows per wave -> 4 accumulators, no cross-lane reduce, no block barrier.
// FIRST: gather f32 row-major h. MODE: 0 none; 1 out = coef*acc; 2 out +=.
// ---------------------------------------------------------------------------
template <int MODE, int FIRST>
__global__ __launch_bounds__(256) void spmm_kernel(
    const u16* __restrict__ dst16, const float* __restrict__ w32,
    const float* __restrict__ hx, const u16* __restrict__ xb,
    u16* __restrict__ y, float* __restrict__ out, float coef) {
  __shared__ u16   s_dst[WPB][RPW * DEGREE];  // 512 B per wave
  __shared__ float s_w[WPB][RPW * DEGREE];    // 1 KB per wave

  const int tid   = threadIdx.x;
  const int b     = blockIdx.x;
  const int slice = b & 7;            // XCD
  const int wb    = b >> 3;           // [0, 256)
  const int wave  = tid >> 6;
  const int lane  = tid & 63;
  const int r2    = lane >> 5;        // which row of the pair
  const int f     = lane & 31;        // feature within slice
  const int row_base = wb * RPB + wave * RPW;

  // wave-local staging of 256 edge records (8 rows x 32 edges); no barrier.
  {
    const int ebase = row_base * DEGREE;
    *(uint2*)&s_dst[wave][lane * 4] = *(const uint2*)(dst16 + ebase + lane * 4);
    *(float4*)&s_w[wave][lane * 4]  = *(const float4*)(w32 + ebase + lane * 4);
  }

  float acc0 = 0.f, acc1 = 0.f, acc2 = 0.f, acc3 = 0.f;

  if (FIRST) {
    const float* __restrict__ hp = hx + slice * SLICE_F + f;
#pragma unroll 4
    for (int j = 0; j < DEGREE; ++j) {
      const int i0 = r2 * DEGREE + j;      // row pair p: index i0 + 64*p
      int   n0 = s_dst[wave][i0      ], n1 = s_dst[wave][i0 +  64];
      int   n2 = s_dst[wave][i0 + 128], n3 = s_dst[wave][i0 + 192];
      float w0 = s_w[wave][i0      ],  w1 = s_w[wave][i0 +  64];
      float w2 = s_w[wave][i0 + 128],  w3 = s_w[wave][i0 + 192];
      acc0 += w0 * hp[n0 * D_FEAT];
      acc1 += w1 * hp[n1 * D_FEAT];
      acc2 += w2 * hp[n2 * D_FEAT];
      acc3 += w3 * hp[n3 * D_FEAT];
    }
  } else {
    const u16* __restrict__ xp = xb + slice * (N_NODES * SLICE_F) + f;
#pragma unroll 4
    for (int j = 0; j < DEGREE; ++j) {
      const int i0 = r2 * DEGREE + j;
      int   n0 = s_dst[wave][i0      ], n1 = s_dst[wave][i0 +  64];
      int   n2 = s_dst[wave][i0 + 128], n3 = s_dst[wave][i0 + 192];
      float w0 = s_w[wave][i0      ],  w1 = s_w[wave][i0 +  64];
      float w2 = s_w[wave][i0 + 128],  w3 = s_w[wave][i0 + 192];
      acc0 += w0 * bf2f(xp[n0 * SLICE_F]);
      acc1 += w1 * bf2f(xp[n1 * SLICE_F]);
      acc2 += w2 * bf2f(xp[n2 * SLICE_F]);
      acc3 += w3 * bf2f(xp[n3 * SLICE_F]);
    }
  }

  // y: element (2p + r2)*32 + f == p*64 + lane -> 128 B coalesced per p
  u16* yp = y + slice * (N_NODES * SLICE_F) + row_base * SLICE_F;
  yp[lane      ] = f2bf(acc0);
  yp[lane +  64] = f2bf(acc1);
  yp[lane + 128] = f2bf(acc2);
  yp[lane + 192] = f2bf(acc3);

  if (MODE) {
    // out row-major: row (2p + r2), feature slice*32 + f
    float* o = out + (size_t)(row_base + r2) * D_FEAT + slice * SLICE_F + f;
    if (MODE == 1) {
      o[0]          = coef * acc0;
      o[2 * D_FEAT] = coef * acc1;
      o[4 * D_FEAT] = coef * acc2;
      o[6 * D_FEAT] = coef * acc3;
    } else {
      o[0]          += coef * acc0;
      o[2 * D_FEAT] += coef * acc1;
      o[4 * D_FEAT] += coef * acc2;
      o[6 * D_FEAT] += coef * acc3;
    }
  }
}

extern "C" void kernel_launch(void* const* d_in, const int* in_sizes, int n_in,
                              void* d_out, int out_size, void* d_ws, size_t ws_size,
                              hipStream_t stream) {
  // inputs: src (unused — structure known), dst (int32), e (f32), h (f32)
  const int*   dst = (const int*)d_in[1];
  const float* e   = (const float*)d_in[2];
  const float* h   = (const float*)d_in[3];
  float* out = (float*)d_out;

  char* ws = (char*)d_ws;
  u16*   buf0  = (u16*)ws;                          // 4 MB sliced bf16
  u16*   buf1  = (u16*)(ws + (size_t)(4u << 20));   // 4 MB sliced bf16
  u16*   dst16 = (u16*)(ws + (size_t)(8u << 20));   // 0.5 MB
  float* w32   = (float*)(ws + (size_t)(9u << 20)); // 1 MB

  prep_kernel<<<N_EDGES / 256, 256, 0, stream>>>(dst, e, dst16, w32);

  u16* bufs[2] = {buf0, buf1};
  int pb = 0;
  const u16* xin = buf0;  // unused on FIRST

  for (int k = 1; k <= 32; ++k) {
    u16* y = bufs[pb];

    float coef; int mode;
    switch (k) {
      case 1:  coef = 1.f;         mode = 1; break;
      case 2:  coef = 1.f;         mode = 2; break;
      case 4:  coef = 1.f / 2.f;   mode = 2; break;
      case 8:  coef = 1.f / 6.f;   mode = 2; break;
      case 16: coef = 1.f / 24.f;  mode = 2; break;
      case 32: coef = 1.f / 120.f; mode = 2; break;
      default: coef = 0.f;         mode = 0; break;
    }

    if (k == 1)
      spmm_kernel<1, 1><<<NB, 256, 0, stream>>>(dst16, w32, h, xin, y, out, coef);
    else if (mode == 0)
      spmm_kernel<0, 0><<<NB, 256, 0, stream>>>(dst16, w32, h, xin, y, out, coef);
    else
      spmm_kernel<2, 0><<<NB, 256, 0, stream>>>(dst16, w32, h, xin, y, out, coef);

    xin = y;
    pb ^= 1;
  }
}

// Round 12
// 417.969 us; speedup vs baseline: 1.2485x; 1.2485x over previous
//
#include <hip/hip_runtime.h>

#define N_NODES 8192
#define DEGREE 32
#define N_EDGES (N_NODES * DEGREE)
#define D_FEAT 256
#define SLICE_F 32                    // features per slice
#define N_SLICES 8                    // bf16 slice = 0.5 MB; slice = XCD affinity
#define RPW 8                         // rows per wave
#define WPB 4                         // waves per block
#define RPB (RPW * WPB)               // 32 rows per block
#define NB (N_SLICES * (N_NODES / RPB))  // 2048 blocks

typedef unsigned int u32;
typedef unsigned short u16;

__device__ __forceinline__ float bflo(u32 v) {
  union { u32 i; float f; } c; c.i = v << 16; return c.f;
}
__device__ __forceinline__ float bfhi(u32 v) {
  union { u32 i; float f; } c; c.i = v & 0xffff0000u; return c.f;
}
__device__ __forceinline__ u32 pack2bf(float a, float b) {
  union { float f; u32 i; } ca, cb;
  ca.f = a; cb.f = b;
  u32 ra = (ca.i + 0x7FFFu + ((ca.i >> 16) & 1u)) >> 16;
  u32 rb = (cb.i + 0x7FFFu + ((cb.i >> 16) & 1u)) & 0xffff0000u;
  return ra | rb;
}

// ---------------------------------------------------------------------------
// Prep: row-normalize once; pack each edge as uint2 { dst*64 (byte offset of
// bf16 slice row), w as f32 bits }. Full-precision weights (numerics match
// round 11 exactly).
// ---------------------------------------------------------------------------
__global__ __launch_bounds__(256) void prep_kernel(
    const int* __restrict__ dst, const float* __restrict__ e,
    uint2* __restrict__ packed) {
  int g = blockIdx.x * 256 + threadIdx.x;
  float v = e[g];
  float s = v;
  for (int m = 1; m < 32; m <<= 1) s += __shfl_xor(s, m, 32);  // rows 32-aligned
  uint2 r;
  r.x = (u32)dst[g] << 6;            // byte offset: dst * SLICE_F * 2
  r.y = __float_as_uint(v / s);
  packed[g] = r;
}

// ---------------------------------------------------------------------------
// y = A @ x, 8-way feature-sliced, bf16 iterate, f32 math — WIDE GATHER.
// x/y layout: [N_SLICES][N_NODES][SLICE_F] bf16 (0.5 MB per slice).
// slice = blockIdx%8 (XCD affinity). Wave: lane = r*8+fg; one gather instr
// covers 8 rows x 8 B (4 bf16 feats)/lane -> 32 gathers/wave total, unroll 8
// keeps 8 dwordx2 loads in flight per wave (the MLP fix).
// Edge records staged wave-locally in LDS [8][34] (conflict-free broadcast).
// FIRST: gather f32 row-major h (float4/lane; h byte off = rec.x*16).
// MODE: 0 none; 1 out = coef*acc; 2 out += coef*acc.
// ---------------------------------------------------------------------------
template <int MODE, int FIRST>
__global__ __launch_bounds__(256) void spmm_kernel(
    const uint2* __restrict__ packed, const float* __restrict__ hx,
    const u16* __restrict__ xb, u16* __restrict__ y,
    float* __restrict__ out, float coef) {
  __shared__ uint2 s_rec[WPB][RPW][34];   // 8704 B; [34] pad -> banks 4r+2j

  const int tid   = threadIdx.x;
  const int b     = blockIdx.x;
  const int slice = b & 7;
  const int wb    = b >> 3;
  const int wave  = tid >> 6;
  const int lane  = tid & 63;
  const int r     = lane >> 3;        // row within wave 0..7
  const int fg    = lane & 7;         // feature group (4 bf16) 0..7
  const int row_base = wb * RPB + wave * RPW;

  // wave-local stage of 256 edge records; coalesced 512 B per instr.
  {
    const uint2* gsrc = packed + row_base * DEGREE;
#pragma unroll
    for (int t = 0; t < 4; ++t) {
      int idx = lane + 64 * t;
      s_rec[wave][idx >> 5][idx & 31] = gsrc[idx];
    }
  }

  float acc0 = 0.f, acc1 = 0.f, acc2 = 0.f, acc3 = 0.f;

  if (FIRST) {
    const char* xrow = (const char*)hx + slice * (SLICE_F * 4) + fg * 16;
#pragma unroll 8
    for (int j = 0; j < DEGREE; ++j) {
      uint2 rec = s_rec[wave][r][j];                 // LDS broadcast per group
      float w = __uint_as_float(rec.y);
      float4 v = *(const float4*)(xrow + ((size_t)rec.x << 4));
      acc0 += w * v.x; acc1 += w * v.y; acc2 += w * v.z; acc3 += w * v.w;
    }
  } else {
    const char* xrow = (const char*)xb + slice * (N_NODES * SLICE_F * 2) + fg * 8;
#pragma unroll 8
    for (int j = 0; j < DEGREE; ++j) {
      uint2 rec = s_rec[wave][r][j];
      float w = __uint_as_float(rec.y);
      uint2 v = *(const uint2*)(xrow + rec.x);       // 8 B/lane, 512 B/instr
      acc0 += w * bflo(v.x); acc1 += w * bfhi(v.x);
      acc2 += w * bflo(v.y); acc3 += w * bfhi(v.y);
    }
  }

  const int row_g = row_base + r;

  // y store: 8 B/lane, 512 B contiguous per wave
  char* yrow = (char*)y + slice * (N_NODES * SLICE_F * 2) + row_g * 64 + fg * 8;
  *(uint2*)yrow = make_uint2(pack2bf(acc0, acc1), pack2bf(acc2, acc3));

  if (MODE) {
    float* o = out + (size_t)row_g * D_FEAT + slice * SLICE_F + fg * 4;
    if (MODE == 1) {
      *(float4*)o = make_float4(coef*acc0, coef*acc1, coef*acc2, coef*acc3);
    } else {
      float4 t = *(float4*)o;
      t.x += coef*acc0; t.y += coef*acc1; t.z += coef*acc2; t.w += coef*acc3;
      *(float4*)o = t;
    }
  }
}

extern "C" void kernel_launch(void* const* d_in, const int* in_sizes, int n_in,
                              void* d_out, int out_size, void* d_ws, size_t ws_size,
                              hipStream_t stream) {
  // inputs: src (unused — structure known), dst (int32), e (f32), h (f32)
  const int*   dst = (const int*)d_in[1];
  const float* e   = (const float*)d_in[2];
  const float* h   = (const float*)d_in[3];
  float* out = (float*)d_out;

  char* ws = (char*)d_ws;
  u16*   buf0   = (u16*)ws;                          // 4 MB sliced bf16
  u16*   buf1   = (u16*)(ws + (size_t)(4u << 20));   // 4 MB sliced bf16
  uint2* packed = (uint2*)(ws + (size_t)(8u << 20)); // 2 MB packed edges

  prep_kernel<<<N_EDGES / 256, 256, 0, stream>>>(dst, e, packed);

  u16* bufs[2] = {buf0, buf1};
  int pb = 0;
  const u16* xin = buf0;  // unused on FIRST

  for (int k = 1; k <= 32; ++k) {
    u16* y = bufs[pb];

    float coef; int mode;
    switch (k) {
      case 1:  coef = 1.f;         mode = 1; break;
      case 2:  coef = 1.f;         mode = 2; break;
      case 4:  coef = 1.f / 2.f;   mode = 2; break;
      case 8:  coef = 1.f / 6.f;   mode = 2; break;
      case 16: coef = 1.f / 24.f;  mode = 2; break;
      case 32: coef = 1.f / 120.f; mode = 2; break;
      default: coef = 0.f;         mode = 0; break;
    }

    if (k == 1)
      spmm_kernel<1, 1><<<NB, 256, 0, stream>>>(packed, h, xin, y, out, coef);
    else if (mode == 0)
      spmm_kernel<0, 0><<<NB, 256, 0, stream>>>(packed, h, xin, y, out, coef);
    else
      spmm_kernel<2, 0><<<NB, 256, 0, stream>>>(packed, h, xin, y, out, coef);

    xin = y;
    pb ^= 1;
  }
}

// Round 13
// 417.952 us; speedup vs baseline: 1.2485x; 1.0000x over previous
//
#include <hip/hip_runtime.h>

#define N_NODES 8192
#define DEGREE 32
#define N_EDGES (N_NODES * DEGREE)
#define D_FEAT 256
#define SLICE_F 32                    // features per slice
#define N_SLICES 8                    // bf16 slice = 0.5 MB; slice = XCD affinity
#define RPW 16                        // rows per wave
#define WPB 4                         // waves per block
#define RPB (RPW * WPB)               // 64 rows per block
#define NB (N_SLICES * (N_NODES / RPB))  // 8 * 128 = 1024 blocks

typedef unsigned int u32;
typedef unsigned short u16;

__device__ __forceinline__ float bflo(u32 v) {
  union { u32 i; float f; } c; c.i = v << 16; return c.f;
}
__device__ __forceinline__ float bfhi(u32 v) {
  union { u32 i; float f; } c; c.i = v & 0xffff0000u; return c.f;
}
__device__ __forceinline__ u32 pack2bf(float a, float b) {
  union { float f; u32 i; } ca, cb;
  ca.f = a; cb.f = b;
  u32 ra = (ca.i + 0x7FFFu + ((ca.i >> 16) & 1u)) >> 16;
  u32 rb = (cb.i + 0x7FFFu + ((cb.i >> 16) & 1u)) & 0xffff0000u;
  return ra | rb;
}

// ---------------------------------------------------------------------------
// Prep: row-normalize once; pack each edge as uint2 { dst*64 (byte offset of
// the bf16 slice row), w as f32 bits }.
// ---------------------------------------------------------------------------
__global__ __launch_bounds__(256) void prep_kernel(
    const int* __restrict__ dst, const float* __restrict__ e,
    uint2* __restrict__ packed) {
  int g = blockIdx.x * 256 + threadIdx.x;
  float v = e[g];
  float s = v;
  for (int m = 1; m < 32; m <<= 1) s += __shfl_xor(s, m, 32);  // rows 32-aligned
  packed[g] = make_uint2((u32)dst[g] << 6, __float_as_uint(v / s));
}

// ---------------------------------------------------------------------------
// y = A @ x, 8-way feature-sliced, bf16 iterate, f32 math — 16 B/lane GATHER.
// x/y layout: [N_SLICES][N_NODES][SLICE_F] bf16 (0.5 MB per slice).
// slice = blockIdx%8 (XCD affinity). Wave: lane = r*4+fg; one gather instr
// covers 16 rows x 16 B/lane (full 64 B slice row per 4-lane group) -> 1 KB
// per instr, 32 instrs per 16 rows (2x fewer VMEM instrs/row than round 12);
// unroll 8 holds 8 KB in flight per wave.
// Edge records in LDS [16][33] (stride 33 -> banks 2(r+j) mod 32: the 16
// 4-lane broadcast groups hit 16 distinct bank pairs -> conflict-free).
// FIRST: gather f32 row-major h (2 x float4 per lane; h byte off = rec.x*16).
// MODE: 0 none; 1 out = coef*acc; 2 out += coef*acc.
// ---------------------------------------------------------------------------
template <int MODE, int FIRST>
__global__ __launch_bounds__(256) void spmm_kernel(
    const uint2* __restrict__ packed, const float* __restrict__ hx,
    const u16* __restrict__ xb, u16* __restrict__ y,
    float* __restrict__ out, float coef) {
  __shared__ uint2 s_rec[WPB][RPW][33];   // 16.9 KB

  const int tid   = threadIdx.x;
  const int b     = blockIdx.x;
  const int slice = b & 7;
  const int wb    = b >> 3;
  const int wave  = tid >> 6;
  const int lane  = tid & 63;
  const int r     = lane >> 2;        // row within wave 0..15
  const int fg    = lane & 3;         // 16 B feature group 0..3
  const int row_base = wb * RPB + wave * RPW;

  // wave-local stage of 512 edge records; coalesced 512 B per instr.
  {
    const uint2* gsrc = packed + row_base * DEGREE;
#pragma unroll
    for (int t = 0; t < 8; ++t) {
      int idx = lane + 64 * t;        // 0..511
      s_rec[wave][idx >> 5][idx & 31] = gsrc[idx];
    }
  }

  float a0=0.f,a1=0.f,a2=0.f,a3=0.f,a4=0.f,a5=0.f,a6=0.f,a7=0.f;

  if (FIRST) {
    const char* xcol = (const char*)hx + slice * (SLICE_F * 4) + fg * 32;
#pragma unroll 4
    for (int j = 0; j < DEGREE; ++j) {
      uint2 rec = s_rec[wave][r][j];               // 4-lane broadcast
      float w = __uint_as_float(rec.y);
      const char* p = xcol + ((size_t)rec.x << 4); // dst*1024
      float4 v0 = *(const float4*)p;
      float4 v1 = *(const float4*)(p + 16);
      a0 += w * v0.x; a1 += w * v0.y; a2 += w * v0.z; a3 += w * v0.w;
      a4 += w * v1.x; a5 += w * v1.y; a6 += w * v1.z; a7 += w * v1.w;
    }
  } else {
    const char* xcol = (const char*)xb + slice * (N_NODES * SLICE_F * 2) + fg * 16;
#pragma unroll 8
    for (int j = 0; j < DEGREE; ++j) {
      uint2 rec = s_rec[wave][r][j];
      float w = __uint_as_float(rec.y);
      uint4 v = *(const uint4*)(xcol + rec.x);     // 16 B/lane, 1 KB/instr
      a0 += w * bflo(v.x); a1 += w * bfhi(v.x);
      a2 += w * bflo(v.y); a3 += w * bfhi(v.y);
      a4 += w * bflo(v.z); a5 += w * bfhi(v.z);
      a6 += w * bflo(v.w); a7 += w * bfhi(v.w);
    }
  }

  const int row_g = row_base + r;

  // y store: 16 B/lane, 1 KB contiguous per wave
  char* yrow = (char*)y + slice * (N_NODES * SLICE_F * 2) + row_g * 64 + fg * 16;
  *(uint4*)yrow = make_uint4(pack2bf(a0, a1), pack2bf(a2, a3),
                             pack2bf(a4, a5), pack2bf(a6, a7));

  if (MODE) {
    float* o = out + (size_t)row_g * D_FEAT + slice * SLICE_F + fg * 8;
    if (MODE == 1) {
      *(float4*)o       = make_float4(coef*a0, coef*a1, coef*a2, coef*a3);
      *(float4*)(o + 4) = make_float4(coef*a4, coef*a5, coef*a6, coef*a7);
    } else {
      float4 t0 = *(float4*)o, t1 = *(float4*)(o + 4);
      t0.x += coef*a0; t0.y += coef*a1; t0.z += coef*a2; t0.w += coef*a3;
      t1.x += coef*a4; t1.y += coef*a5; t1.z += coef*a6; t1.w += coef*a7;
      *(float4*)o = t0; *(float4*)(o + 4) = t1;
    }
  }
}

extern "C" void kernel_launch(void* const* d_in, const int* in_sizes, int n_in,
                              void* d_out, int out_size, void* d_ws, size_t ws_size,
                              hipStream_t stream) {
  // inputs: src (unused — structure known), dst (int32), e (f32), h (f32)
  const int*   dst = (const int*)d_in[1];
  const float* e   = (const float*)d_in[2];
  const float* h   = (const float*)d_in[3];
  float* out = (float*)d_out;

  char* ws = (char*)d_ws;
  u16*   buf0   = (u16*)ws;                          // 4 MB sliced bf16
  u16*   buf1   = (u16*)(ws + (size_t)(4u << 20));   // 4 MB sliced bf16
  uint2* packed = (uint2*)(ws + (size_t)(8u << 20)); // 2 MB packed edges

  prep_kernel<<<N_EDGES / 256, 256, 0, stream>>>(dst, e, packed);

  u16* bufs[2] = {buf0, buf1};
  int pb = 0;
  const u16* xin = buf0;  // unused on FIRST

  for (int k = 1; k <= 32; ++k) {
    u16* y = bufs[pb];

    float coef; int mode;
    switch (k) {
      case 1:  coef = 1.f;         mode = 1; break;
      case 2:  coef = 1.f;         mode = 2; break;
      case 4:  coef = 1.f / 2.f;   mode = 2; break;
      case 8:  coef = 1.f / 6.f;   mode = 2; break;
      case 16: coef = 1.f / 24.f;  mode = 2; break;
      case 32: coef = 1.f / 120.f; mode = 2; break;
      default: coef = 0.f;         mode = 0; break;
    }

    if (k == 1)
      spmm_kernel<1, 1><<<NB, 256, 0, stream>>>(packed, h, xin, y, out, coef);
    else if (mode == 0)
      spmm_kernel<0, 0><<<NB, 256, 0, stream>>>(packed, h, xin, y, out, coef);
    else
      spmm_kernel<2, 0><<<NB, 256, 0, stream>>>(packed, h, xin, y, out, coef);

    xin = y;
    pb ^= 1;
  }
}